// Round 1
// baseline (809.716 us; speedup 1.0000x reference)
//
#include <hip/hip_runtime.h>
#include <math.h>

// ---------------------------------------------------------------------------
// MPNNPropPred: N=20000 nodes, E=50000 edges, B=128 graphs, H=64,
// FEAT=28, N_TYPES=100, EDGE_DIM=5, MP_ITER=3, S2S_ITER=4, OUT=1. All f32.
// ---------------------------------------------------------------------------

#define NN 20000
#define NE 50000
#define NB 128
#define HD 64
#define NFEAT 28
#define NTYPES 100
#define EDIM 5
#define MPIT 3
#define S2SIT 4

__device__ __forceinline__ float lane_bcast(float v, int l) {
  return __int_as_float(__builtin_amdgcn_readlane(__float_as_int(v), l));
}

__device__ __forceinline__ float sigm(float x) {
  return 1.0f / (1.0f + expf(-x));
}

// --- 5 edge-type weight matrices: Wty[t][k*64+o] = relu(W_e1[t]+b_e1) @ W_e2 + b_e2
__global__ void k_edgemats(const float* __restrict__ W_e1, const float* __restrict__ b_e1,
                           const float* __restrict__ W_e2, const float* __restrict__ b_e2,
                           float* __restrict__ Wty) {
  __shared__ float v[HD];
  int t = blockIdx.x >> 2;       // 5 types
  int chunk = blockIdx.x & 3;    // 4 chunks of 1024
  int tid = threadIdx.x;
  if (tid < HD) {
    float x = W_e1[t * HD + tid] + b_e1[tid];
    v[tid] = x > 0.f ? x : 0.f;
  }
  __syncthreads();
  #pragma unroll
  for (int i = 0; i < 4; ++i) {
    int m = chunk * 1024 + i * 256 + tid;
    float acc = b_e2[m];
    #pragma unroll
    for (int j = 0; j < HD; ++j)
      acc = fmaf(v[j], W_e2[j * 4096 + m], acc);
    Wty[t * 4096 + m] = acc;
  }
}

// --- node embedding: h[n][j] = W_emb[type[n]][j] + b_emb[j] + sum_f feat[n][f]*W_emb[100+f][j]
__global__ void k_embed(const float* __restrict__ feat, const int* __restrict__ ntype,
                        const float* __restrict__ W_emb, const float* __restrict__ b_emb,
                        float* __restrict__ h) {
  int lane = threadIdx.x & 63;
  int n = (blockIdx.x * blockDim.x + threadIdx.x) >> 6;  // wave-uniform
  if (n >= NN) return;
  int t = ntype[n];                                       // broadcast load
  float fv = (lane < NFEAT) ? feat[n * NFEAT + lane] : 0.f;
  float acc = b_emb[lane] + W_emb[t * HD + lane];
  #pragma unroll
  for (int f = 0; f < NFEAT; ++f)
    acc = fmaf(lane_bcast(fv, f), W_emb[(NTYPES + f) * HD + lane], acc);
  h[n * HD + lane] = acc;
}

// --- counting sort of edges by type ---
__global__ void k_hist(const int* __restrict__ etype, int* __restrict__ counts) {
  int e = blockIdx.x * blockDim.x + threadIdx.x;
  if (e < NE) atomicAdd(&counts[etype[e]], 1);
}

__global__ void k_scan(const int* __restrict__ counts, int* __restrict__ offs,
                       int* __restrict__ cursor) {
  if (threadIdx.x == 0 && blockIdx.x == 0) {
    int s = 0;
    for (int t = 0; t < EDIM; ++t) { offs[t] = s; cursor[t] = s; s += counts[t]; }
    offs[EDIM] = s;
  }
}

__global__ void k_scatter(const int* __restrict__ etype, int* __restrict__ cursor,
                          int* __restrict__ sorted) {
  int e = blockIdx.x * blockDim.x + threadIdx.x;
  if (e < NE) {
    int p = atomicAdd(&cursor[etype[e]], 1);
    sorted[p] = e;
  }
}

// --- CSR starts for sorted batch vector ---
__global__ void k_starts(const int* __restrict__ batch, int* __restrict__ start) {
  int n = blockIdx.x * blockDim.x + threadIdx.x;
  if (n >= NN) return;
  int b = batch[n];
  if (n == 0)
    for (int t = 0; t <= b; ++t) start[t] = 0;
  int bn = (n + 1 < NN) ? batch[n + 1] : NB;
  for (int t = b + 1; t <= bn; ++t) start[t] = n + 1;
}

// --- root: hnext[n][o] = bias[o] + sum_k h[n][k]*root[k][o]  (also inits hnext)
__global__ void k_root(const float* __restrict__ h, float* __restrict__ hnext,
                       const float* __restrict__ root, const float* __restrict__ bias) {
  int lane = threadIdx.x & 63;
  int wid = blockIdx.x * (blockDim.x >> 6) + (threadIdx.x >> 6);
  int nw = gridDim.x * (blockDim.x >> 6);
  float w[HD];
  #pragma unroll
  for (int k = 0; k < HD; ++k) w[k] = root[k * HD + lane];
  float bb = bias[lane];
  for (int n = wid; n < NN; n += nw) {
    float hval = h[n * HD + lane];
    float a0 = 0.f, a1 = 0.f, a2 = 0.f, a3 = 0.f;
    #pragma unroll
    for (int k = 0; k < HD; k += 4) {
      a0 = fmaf(lane_bcast(hval, k + 0), w[k + 0], a0);
      a1 = fmaf(lane_bcast(hval, k + 1), w[k + 1], a1);
      a2 = fmaf(lane_bcast(hval, k + 2), w[k + 2], a2);
      a3 = fmaf(lane_bcast(hval, k + 3), w[k + 3], a3);
    }
    hnext[n * HD + lane] = bb + ((a0 + a1) + (a2 + a3));
  }
}

// --- edge messages: hnext[dst] += h[src] @ W_{type}; one wave per edge,
//     W column in VGPRs (edges sorted by type), h[src] broadcast via readlane.
__global__ void k_msg(const int* __restrict__ sorted, const int* __restrict__ ei,
                      const int* __restrict__ offs, const float* __restrict__ Wty,
                      const float* __restrict__ h, float* __restrict__ hnext) {
  int lane = threadIdx.x & 63;
  int wid = blockIdx.x * (blockDim.x >> 6) + (threadIdx.x >> 6);
  int nw = gridDim.x * (blockDim.x >> 6);
  int per = (NE + nw - 1) / nw;
  int beg = wid * per;
  int end = beg + per; if (end > NE) end = NE;
  if (beg >= end) return;
  for (int t = 0; t < EDIM; ++t) {
    int lo = offs[t];     if (lo < beg) lo = beg;
    int hi = offs[t + 1]; if (hi > end) hi = end;
    if (lo >= hi) continue;
    float w[HD];
    #pragma unroll
    for (int k = 0; k < HD; ++k) w[k] = Wty[t * 4096 + k * HD + lane];
    for (int p = lo; p < hi; ++p) {
      int e = sorted[p];          // wave-uniform
      int s = ei[e];
      int d = ei[NE + e];
      float hval = h[s * HD + lane];
      float a0 = 0.f, a1 = 0.f, a2 = 0.f, a3 = 0.f;
      #pragma unroll
      for (int k = 0; k < HD; k += 4) {
        a0 = fmaf(lane_bcast(hval, k + 0), w[k + 0], a0);
        a1 = fmaf(lane_bcast(hval, k + 1), w[k + 1], a1);
        a2 = fmaf(lane_bcast(hval, k + 2), w[k + 2], a2);
        a3 = fmaf(lane_bcast(hval, k + 3), w[k + 3], a3);
      }
      atomicAdd(&hnext[d * HD + lane], (a0 + a1) + (a2 + a3));
    }
  }
}

// --- Set2Set (4 iters, per-graph independent) + output MLP, one block per graph
__global__ void k_s2s(const float* __restrict__ h, const int* __restrict__ gstart,
                      const float* __restrict__ W_ih, const float* __restrict__ W_hh,
                      const float* __restrict__ b_ih, const float* __restrict__ b_hh,
                      const float* __restrict__ W_o1, const float* __restrict__ b_o1,
                      const float* __restrict__ W_o2, const float* __restrict__ b_o2,
                      float* __restrict__ out) {
  __shared__ float qstar[2 * HD];
  __shared__ float hxs[HD], cxs[HD], gates[4 * HD];
  __shared__ float redM[4], redS[4], redR[4][HD];
  __shared__ float hid[HD];
  int b = blockIdx.x;
  int tid = threadIdx.x;
  int lane = tid & 63, wv = tid >> 6;
  int st = gstart[b], en = gstart[b + 1];
  if (tid < 2 * HD) qstar[tid] = 0.f;
  if (tid < HD) { hxs[tid] = 0.f; cxs[tid] = 0.f; }
  __syncthreads();

  for (int it = 0; it < S2SIT; ++it) {
    // LSTM gates: tid = gate index g in [0,256)
    float acc = b_ih[tid] + b_hh[tid];
    const float4* wi4 = reinterpret_cast<const float4*>(W_ih + tid * 2 * HD);
    #pragma unroll 8
    for (int j = 0; j < 32; ++j) {
      float4 wvv = wi4[j];
      acc = fmaf(qstar[4 * j + 0], wvv.x, acc);
      acc = fmaf(qstar[4 * j + 1], wvv.y, acc);
      acc = fmaf(qstar[4 * j + 2], wvv.z, acc);
      acc = fmaf(qstar[4 * j + 3], wvv.w, acc);
    }
    const float4* wh4 = reinterpret_cast<const float4*>(W_hh + tid * HD);
    #pragma unroll 8
    for (int j = 0; j < 16; ++j) {
      float4 wvv = wh4[j];
      acc = fmaf(hxs[4 * j + 0], wvv.x, acc);
      acc = fmaf(hxs[4 * j + 1], wvv.y, acc);
      acc = fmaf(hxs[4 * j + 2], wvv.z, acc);
      acc = fmaf(hxs[4 * j + 3], wvv.w, acc);
    }
    gates[tid] = acc;
    __syncthreads();
    if (tid < HD) {
      float ig = sigm(gates[tid]);
      float fg = sigm(gates[HD + tid]);
      float gg = tanhf(gates[2 * HD + tid]);
      float og = sigm(gates[3 * HD + tid]);
      float c = fmaf(fg, cxs[tid], ig * gg);
      cxs[tid] = c;
      hxs[tid] = og * tanhf(c);
    }
    __syncthreads();

    // attention with online softmax; 4 waves stride the node range
    float q = hxs[lane];
    float m = -1e30f, s = 0.f, r = 0.f;
    for (int n = st + wv; n < en; n += 4) {
      float v = h[n * HD + lane];
      float e = v * q;
      #pragma unroll
      for (int off = 32; off; off >>= 1) e += __shfl_xor(e, off, 64);
      float mn = fmaxf(m, e);
      float sc = expf(m - mn);       // 0 on first node (m=-1e30)
      float wgt = expf(e - mn);
      s = fmaf(s, sc, wgt);
      r = fmaf(r, sc, wgt * v);
      m = mn;
    }
    if (lane == 0) { redM[wv] = m; redS[wv] = s; }
    redR[wv][lane] = r;
    __syncthreads();
    if (tid < HD) {
      float M = fmaxf(fmaxf(redM[0], redM[1]), fmaxf(redM[2], redM[3]));
      float S = 0.f, R = 0.f;
      #pragma unroll
      for (int k = 0; k < 4; ++k) {
        float sc = expf(redM[k] - M);   // exp(0)=1 if both -1e30; S stays 0
        S = fmaf(redS[k], sc, S);
        R = fmaf(redR[k][tid], sc, R);
      }
      if (S == 0.f) S = 1.f;            // empty-graph guard (matches ref)
      qstar[tid] = hxs[tid];
      qstar[HD + tid] = R / S;
    }
    __syncthreads();
  }

  // output MLP: relu(qstar @ W_o1 + b_o1) @ W_o2 + b_o2
  if (tid < HD) {
    float acc = b_o1[tid];
    #pragma unroll 8
    for (int i = 0; i < 2 * HD; ++i)
      acc = fmaf(qstar[i], W_o1[i * HD + tid], acc);
    hid[tid] = acc > 0.f ? acc : 0.f;
  }
  __syncthreads();
  if (tid < HD) {
    float p = hid[tid] * W_o2[tid];
    #pragma unroll
    for (int off = 32; off; off >>= 1) p += __shfl_xor(p, off, 64);
    if (tid == 0) out[b] = p + b_o2[0];
  }
}

extern "C" void kernel_launch(void* const* d_in, const int* in_sizes, int n_in,
                              void* d_out, int out_size, void* d_ws, size_t ws_size,
                              hipStream_t stream) {
  const float* node_feat = (const float*)d_in[0];
  const int*   node_type = (const int*)d_in[1];
  const int*   edge_index= (const int*)d_in[2];
  const int*   edge_type = (const int*)d_in[3];
  const int*   batch     = (const int*)d_in[4];
  const float* W_emb     = (const float*)d_in[5];
  const float* b_emb     = (const float*)d_in[6];
  const float* W_e1      = (const float*)d_in[7];
  const float* b_e1      = (const float*)d_in[8];
  const float* W_e2      = (const float*)d_in[9];
  const float* b_e2      = (const float*)d_in[10];
  const float* roots     = (const float*)d_in[11];
  const float* conv_bias = (const float*)d_in[12];
  const float* W_ih      = (const float*)d_in[13];
  const float* W_hh      = (const float*)d_in[14];
  const float* b_ih      = (const float*)d_in[15];
  const float* b_hh      = (const float*)d_in[16];
  const float* W_o1      = (const float*)d_in[17];
  const float* b_o1      = (const float*)d_in[18];
  const float* W_o2      = (const float*)d_in[19];
  const float* b_o2      = (const float*)d_in[20];
  float* out = (float*)d_out;

  // workspace layout (floats/ints), base assumed 256B-aligned
  float* Wty    = (float*)d_ws;            // 5*4096
  float* hA     = Wty + EDIM * 4096;       // NN*64
  float* hB     = hA + NN * HD;            // NN*64
  int*   sorted = (int*)(hB + NN * HD);    // NE
  int*   counts = sorted + NE;             // 8
  int*   offs   = counts + 8;              // 8
  int*   cursor = offs + 8;                // 8
  int*   gstart = cursor + 8;              // NB+1

  hipMemsetAsync(counts, 0, EDIM * sizeof(int), stream);

  k_edgemats<<<EDIM * 4, 256, 0, stream>>>(W_e1, b_e1, W_e2, b_e2, Wty);
  k_embed<<<(NN * HD) / 256, 256, 0, stream>>>(node_feat, node_type, W_emb, b_emb, hA);
  k_hist<<<(NE + 255) / 256, 256, 0, stream>>>(edge_type, counts);
  k_scan<<<1, 64, 0, stream>>>(counts, offs, cursor);
  k_scatter<<<(NE + 255) / 256, 256, 0, stream>>>(edge_type, cursor, sorted);
  k_starts<<<(NN + 255) / 256, 256, 0, stream>>>(batch, gstart);

  const float* hcur = hA;
  float* hnxt = hB;
  for (int i = 0; i < MPIT; ++i) {
    k_root<<<512, 256, 0, stream>>>(hcur, hnxt, roots + i * HD * HD, conv_bias + i * HD);
    k_msg<<<1024, 256, 0, stream>>>(sorted, edge_index, offs, Wty, hcur, hnxt);
    const float* tmp = hnxt; hnxt = (float*)hcur; hcur = tmp;
  }

  k_s2s<<<NB, 256, 0, stream>>>(hcur, gstart, W_ih, W_hh, b_ih, b_hh,
                                W_o1, b_o1, W_o2, b_o2, out);
}

// Round 2
// 342.474 us; speedup vs baseline: 2.3643x; 2.3643x over previous
//
#include <hip/hip_runtime.h>
#include <math.h>

// ---------------------------------------------------------------------------
// MPNNPropPred: N=20000 nodes, E=50000 edges, B=128 graphs, H=64,
// FEAT=28, N_TYPES=100, EDGE_DIM=5, MP_ITER=3, S2S_IT=4, OUT=1. All f32.
// R2: atomic-free ballot counting sort (old k_hist/k_scatter: 2x237us of
//     serialized global atomics on 5 counters).
// ---------------------------------------------------------------------------

#define NN 20000
#define NE 50000
#define NB 128
#define HD 64
#define NFEAT 28
#define NTYPES 100
#define EDIM 5
#define MPIT 3
#define S2SIT 4
#define NBLK ((NE + 255) / 256)   // 196 blocks for the sort kernels

__device__ __forceinline__ float lane_bcast(float v, int l) {
  return __int_as_float(__builtin_amdgcn_readlane(__float_as_int(v), l));
}

__device__ __forceinline__ float sigm(float x) {
  return 1.0f / (1.0f + expf(-x));
}

// --- 5 edge-type weight matrices: Wty[t][k*64+o] = relu(W_e1[t]+b_e1) @ W_e2 + b_e2
__global__ void k_edgemats(const float* __restrict__ W_e1, const float* __restrict__ b_e1,
                           const float* __restrict__ W_e2, const float* __restrict__ b_e2,
                           float* __restrict__ Wty) {
  __shared__ float v[HD];
  int t = blockIdx.x >> 2;       // 5 types
  int chunk = blockIdx.x & 3;    // 4 chunks of 1024
  int tid = threadIdx.x;
  if (tid < HD) {
    float x = W_e1[t * HD + tid] + b_e1[tid];
    v[tid] = x > 0.f ? x : 0.f;
  }
  __syncthreads();
  #pragma unroll
  for (int i = 0; i < 4; ++i) {
    int m = chunk * 1024 + i * 256 + tid;
    float acc = b_e2[m];
    #pragma unroll
    for (int j = 0; j < HD; ++j)
      acc = fmaf(v[j], W_e2[j * 4096 + m], acc);
    Wty[t * 4096 + m] = acc;
  }
}

// --- node embedding: h[n][j] = W_emb[type[n]][j] + b_emb[j] + sum_f feat[n][f]*W_emb[100+f][j]
__global__ void k_embed(const float* __restrict__ feat, const int* __restrict__ ntype,
                        const float* __restrict__ W_emb, const float* __restrict__ b_emb,
                        float* __restrict__ h) {
  int lane = threadIdx.x & 63;
  int n = (blockIdx.x * blockDim.x + threadIdx.x) >> 6;  // wave-uniform
  if (n >= NN) return;
  int t = ntype[n];                                       // broadcast load
  float fv = (lane < NFEAT) ? feat[n * NFEAT + lane] : 0.f;
  float acc = b_emb[lane] + W_emb[t * HD + lane];
  #pragma unroll
  for (int f = 0; f < NFEAT; ++f)
    acc = fmaf(lane_bcast(fv, f), W_emb[(NTYPES + f) * HD + lane], acc);
  h[n * HD + lane] = acc;
}

// --- atomic-free counting sort of edges by type (3 phases) ---
// phase 1: per-block per-type counts via ballot
__global__ void k_cnt(const int* __restrict__ etype, int* __restrict__ bc) {
  int tid = threadIdx.x, lane = tid & 63, wv = tid >> 6;
  int e = blockIdx.x * 256 + tid;
  int ty = (e < NE) ? etype[e] : -1;
  __shared__ int wc[4][EDIM];
  #pragma unroll
  for (int t = 0; t < EDIM; ++t) {
    unsigned long long m = __ballot(ty == t);
    if (lane == 0) wc[wv][t] = __popcll(m);
  }
  __syncthreads();
  if (tid < EDIM) {
    int s = 0;
    #pragma unroll
    for (int w = 0; w < 4; ++w) s += wc[w][tid];
    bc[blockIdx.x * EDIM + tid] = s;
  }
}

// phase 2: single-block scan -> per-block type bases + global type offsets
__global__ void k_scan(const int* __restrict__ bc, int* __restrict__ blockbase,
                       int* __restrict__ offs) {
  __shared__ int tot[EDIM];
  int t = threadIdx.x;
  if (t < EDIM) {
    int s = 0;
    for (int b = 0; b < NBLK; ++b) s += bc[b * EDIM + t];
    tot[t] = s;
  }
  __syncthreads();
  if (t < EDIM) {
    int start = 0;
    for (int u = 0; u < t; ++u) start += tot[u];
    offs[t] = start;
    if (t == EDIM - 1) offs[EDIM] = start + tot[t];
    int run = start;
    for (int b = 0; b < NBLK; ++b) {
      blockbase[b * EDIM + t] = run;
      run += bc[b * EDIM + t];
    }
  }
}

// phase 3: placement via ballot ranks (no atomics)
__global__ void k_place(const int* __restrict__ etype, const int* __restrict__ blockbase,
                        int* __restrict__ sorted) {
  int tid = threadIdx.x, lane = tid & 63, wv = tid >> 6;
  int e = blockIdx.x * 256 + tid;
  int ty = (e < NE) ? etype[e] : -1;
  __shared__ int wc[4][EDIM];
  int rank = 0;
  #pragma unroll
  for (int t = 0; t < EDIM; ++t) {
    unsigned long long m = __ballot(ty == t);
    if (lane == 0) wc[wv][t] = __popcll(m);
    if (ty == t) rank = __popcll(m & ((1ull << lane) - 1ull));
  }
  __syncthreads();
  if (ty >= 0) {
    int base = blockbase[blockIdx.x * EDIM + ty];
    for (int w = 0; w < wv; ++w) base += wc[w][ty];
    sorted[base + rank] = e;
  }
}

// --- CSR starts for sorted batch vector ---
__global__ void k_starts(const int* __restrict__ batch, int* __restrict__ start) {
  int n = blockIdx.x * blockDim.x + threadIdx.x;
  if (n >= NN) return;
  int b = batch[n];
  if (n == 0)
    for (int t = 0; t <= b; ++t) start[t] = 0;
  int bn = (n + 1 < NN) ? batch[n + 1] : NB;
  for (int t = b + 1; t <= bn; ++t) start[t] = n + 1;
}

// --- root: hnext[n][o] = bias[o] + sum_k h[n][k]*root[k][o]  (also inits hnext)
__global__ void k_root(const float* __restrict__ h, float* __restrict__ hnext,
                       const float* __restrict__ root, const float* __restrict__ bias) {
  int lane = threadIdx.x & 63;
  int wid = blockIdx.x * (blockDim.x >> 6) + (threadIdx.x >> 6);
  int nw = gridDim.x * (blockDim.x >> 6);
  float w[HD];
  #pragma unroll
  for (int k = 0; k < HD; ++k) w[k] = root[k * HD + lane];
  float bb = bias[lane];
  for (int n = wid; n < NN; n += nw) {
    float hval = h[n * HD + lane];
    float a0 = 0.f, a1 = 0.f, a2 = 0.f, a3 = 0.f;
    #pragma unroll
    for (int k = 0; k < HD; k += 4) {
      a0 = fmaf(lane_bcast(hval, k + 0), w[k + 0], a0);
      a1 = fmaf(lane_bcast(hval, k + 1), w[k + 1], a1);
      a2 = fmaf(lane_bcast(hval, k + 2), w[k + 2], a2);
      a3 = fmaf(lane_bcast(hval, k + 3), w[k + 3], a3);
    }
    hnext[n * HD + lane] = bb + ((a0 + a1) + (a2 + a3));
  }
}

// --- edge messages: hnext[dst] += h[src] @ W_{type}; one wave per edge,
//     W column in VGPRs (edges sorted by type), h[src] broadcast via readlane.
__global__ void k_msg(const int* __restrict__ sorted, const int* __restrict__ ei,
                      const int* __restrict__ offs, const float* __restrict__ Wty,
                      const float* __restrict__ h, float* __restrict__ hnext) {
  int lane = threadIdx.x & 63;
  int wid = blockIdx.x * (blockDim.x >> 6) + (threadIdx.x >> 6);
  int nw = gridDim.x * (blockDim.x >> 6);
  int per = (NE + nw - 1) / nw;
  int beg = wid * per;
  int end = beg + per; if (end > NE) end = NE;
  if (beg >= end) return;
  for (int t = 0; t < EDIM; ++t) {
    int lo = offs[t];     if (lo < beg) lo = beg;
    int hi = offs[t + 1]; if (hi > end) hi = end;
    if (lo >= hi) continue;
    float w[HD];
    #pragma unroll
    for (int k = 0; k < HD; ++k) w[k] = Wty[t * 4096 + k * HD + lane];
    for (int p = lo; p < hi; ++p) {
      int e = sorted[p];          // wave-uniform
      int s = ei[e];
      int d = ei[NE + e];
      float hval = h[s * HD + lane];
      float a0 = 0.f, a1 = 0.f, a2 = 0.f, a3 = 0.f;
      #pragma unroll
      for (int k = 0; k < HD; k += 4) {
        a0 = fmaf(lane_bcast(hval, k + 0), w[k + 0], a0);
        a1 = fmaf(lane_bcast(hval, k + 1), w[k + 1], a1);
        a2 = fmaf(lane_bcast(hval, k + 2), w[k + 2], a2);
        a3 = fmaf(lane_bcast(hval, k + 3), w[k + 3], a3);
      }
      atomicAdd(&hnext[d * HD + lane], (a0 + a1) + (a2 + a3));
    }
  }
}

// --- Set2Set (4 iters, per-graph independent) + output MLP, one block per graph
__global__ void k_s2s(const float* __restrict__ h, const int* __restrict__ gstart,
                      const float* __restrict__ W_ih, const float* __restrict__ W_hh,
                      const float* __restrict__ b_ih, const float* __restrict__ b_hh,
                      const float* __restrict__ W_o1, const float* __restrict__ b_o1,
                      const float* __restrict__ W_o2, const float* __restrict__ b_o2,
                      float* __restrict__ out) {
  __shared__ float qstar[2 * HD];
  __shared__ float hxs[HD], cxs[HD], gates[4 * HD];
  __shared__ float redM[4], redS[4], redR[4][HD];
  __shared__ float hid[HD];
  int b = blockIdx.x;
  int tid = threadIdx.x;
  int lane = tid & 63, wv = tid >> 6;
  int st = gstart[b], en = gstart[b + 1];
  if (tid < 2 * HD) qstar[tid] = 0.f;
  if (tid < HD) { hxs[tid] = 0.f; cxs[tid] = 0.f; }
  __syncthreads();

  for (int it = 0; it < S2SIT; ++it) {
    // LSTM gates: tid = gate index g in [0,256)
    float acc = b_ih[tid] + b_hh[tid];
    const float4* wi4 = reinterpret_cast<const float4*>(W_ih + tid * 2 * HD);
    #pragma unroll 8
    for (int j = 0; j < 32; ++j) {
      float4 wvv = wi4[j];
      acc = fmaf(qstar[4 * j + 0], wvv.x, acc);
      acc = fmaf(qstar[4 * j + 1], wvv.y, acc);
      acc = fmaf(qstar[4 * j + 2], wvv.z, acc);
      acc = fmaf(qstar[4 * j + 3], wvv.w, acc);
    }
    const float4* wh4 = reinterpret_cast<const float4*>(W_hh + tid * HD);
    #pragma unroll 8
    for (int j = 0; j < 16; ++j) {
      float4 wvv = wh4[j];
      acc = fmaf(hxs[4 * j + 0], wvv.x, acc);
      acc = fmaf(hxs[4 * j + 1], wvv.y, acc);
      acc = fmaf(hxs[4 * j + 2], wvv.z, acc);
      acc = fmaf(hxs[4 * j + 3], wvv.w, acc);
    }
    gates[tid] = acc;
    __syncthreads();
    if (tid < HD) {
      float ig = sigm(gates[tid]);
      float fg = sigm(gates[HD + tid]);
      float gg = tanhf(gates[2 * HD + tid]);
      float og = sigm(gates[3 * HD + tid]);
      float c = fmaf(fg, cxs[tid], ig * gg);
      cxs[tid] = c;
      hxs[tid] = og * tanhf(c);
    }
    __syncthreads();

    // attention with online softmax; 4 waves stride the node range
    float q = hxs[lane];
    float m = -1e30f, s = 0.f, r = 0.f;
    for (int n = st + wv; n < en; n += 4) {
      float v = h[n * HD + lane];
      float e = v * q;
      #pragma unroll
      for (int off = 32; off; off >>= 1) e += __shfl_xor(e, off, 64);
      float mn = fmaxf(m, e);
      float sc = expf(m - mn);       // 0 on first node (m=-1e30)
      float wgt = expf(e - mn);
      s = fmaf(s, sc, wgt);
      r = fmaf(r, sc, wgt * v);
      m = mn;
    }
    if (lane == 0) { redM[wv] = m; redS[wv] = s; }
    redR[wv][lane] = r;
    __syncthreads();
    if (tid < HD) {
      float M = fmaxf(fmaxf(redM[0], redM[1]), fmaxf(redM[2], redM[3]));
      float S = 0.f, R = 0.f;
      #pragma unroll
      for (int k = 0; k < 4; ++k) {
        float sc = expf(redM[k] - M);   // exp(0)=1 if both -1e30; S stays 0
        S = fmaf(redS[k], sc, S);
        R = fmaf(redR[k][tid], sc, R);
      }
      if (S == 0.f) S = 1.f;            // empty-graph guard (matches ref)
      qstar[tid] = hxs[tid];
      qstar[HD + tid] = R / S;
    }
    __syncthreads();
  }

  // output MLP: relu(qstar @ W_o1 + b_o1) @ W_o2 + b_o2
  if (tid < HD) {
    float acc = b_o1[tid];
    #pragma unroll 8
    for (int i = 0; i < 2 * HD; ++i)
      acc = fmaf(qstar[i], W_o1[i * HD + tid], acc);
    hid[tid] = acc > 0.f ? acc : 0.f;
  }
  __syncthreads();
  if (tid < HD) {
    float p = hid[tid] * W_o2[tid];
    #pragma unroll
    for (int off = 32; off; off >>= 1) p += __shfl_xor(p, off, 64);
    if (tid == 0) out[b] = p + b_o2[0];
  }
}

extern "C" void kernel_launch(void* const* d_in, const int* in_sizes, int n_in,
                              void* d_out, int out_size, void* d_ws, size_t ws_size,
                              hipStream_t stream) {
  const float* node_feat = (const float*)d_in[0];
  const int*   node_type = (const int*)d_in[1];
  const int*   edge_index= (const int*)d_in[2];
  const int*   edge_type = (const int*)d_in[3];
  const int*   batch     = (const int*)d_in[4];
  const float* W_emb     = (const float*)d_in[5];
  const float* b_emb     = (const float*)d_in[6];
  const float* W_e1      = (const float*)d_in[7];
  const float* b_e1      = (const float*)d_in[8];
  const float* W_e2      = (const float*)d_in[9];
  const float* b_e2      = (const float*)d_in[10];
  const float* roots     = (const float*)d_in[11];
  const float* conv_bias = (const float*)d_in[12];
  const float* W_ih      = (const float*)d_in[13];
  const float* W_hh      = (const float*)d_in[14];
  const float* b_ih      = (const float*)d_in[15];
  const float* b_hh      = (const float*)d_in[16];
  const float* W_o1      = (const float*)d_in[17];
  const float* b_o1      = (const float*)d_in[18];
  const float* W_o2      = (const float*)d_in[19];
  const float* b_o2      = (const float*)d_in[20];
  float* out = (float*)d_out;

  // workspace layout (floats/ints), base assumed 256B-aligned
  float* Wty    = (float*)d_ws;             // 5*4096
  float* hA     = Wty + EDIM * 4096;        // NN*64
  float* hB     = hA + NN * HD;             // NN*64
  int*   sorted = (int*)(hB + NN * HD);     // NE
  int*   bc     = sorted + NE;              // NBLK*EDIM
  int*   bbase  = bc + NBLK * EDIM;         // NBLK*EDIM
  int*   offs   = bbase + NBLK * EDIM;      // EDIM+1 (pad 8)
  int*   gstart = offs + 8;                 // NB+1

  k_edgemats<<<EDIM * 4, 256, 0, stream>>>(W_e1, b_e1, W_e2, b_e2, Wty);
  k_embed<<<(NN * HD) / 256, 256, 0, stream>>>(node_feat, node_type, W_emb, b_emb, hA);
  k_cnt<<<NBLK, 256, 0, stream>>>(edge_type, bc);
  k_scan<<<1, 64, 0, stream>>>(bc, bbase, offs);
  k_place<<<NBLK, 256, 0, stream>>>(edge_type, bbase, sorted);
  k_starts<<<(NN + 255) / 256, 256, 0, stream>>>(batch, gstart);

  const float* hcur = hA;
  float* hnxt = hB;
  for (int i = 0; i < MPIT; ++i) {
    k_root<<<512, 256, 0, stream>>>(hcur, hnxt, roots + i * HD * HD, conv_bias + i * HD);
    k_msg<<<1024, 256, 0, stream>>>(sorted, edge_index, offs, Wty, hcur, hnxt);
    const float* tmp = hnxt; hnxt = (float*)hcur; hcur = tmp;
  }

  k_s2s<<<NB, 256, 0, stream>>>(hcur, gstart, W_ih, W_hh, b_ih, b_hh,
                                W_o1, b_o1, W_o2, b_o2, out);
}

// Round 3
// 312.924 us; speedup vs baseline: 2.5876x; 1.0944x over previous
//
#include <hip/hip_runtime.h>
#include <math.h>

// ---------------------------------------------------------------------------
// MPNNPropPred: N=20000 nodes, E=50000 edges, B=128 graphs, H=64,
// FEAT=28, N_TYPES=100, EDGE_DIM=5, MP_ITER=3, S2S_IT=4, OUT=1. All f32.
// R3: k_s2s LDS-resident two-pass softmax (was 109us latency-bound);
//     parallel k_scan; k_msg depth-2 pipelined with presorted src/dst.
// ---------------------------------------------------------------------------

#define NN 20000
#define NE 50000
#define NB 128
#define HD 64
#define NFEAT 28
#define NTYPES 100
#define EDIM 5
#define MPIT 3
#define S2SIT 4
#define NBLK ((NE + 255) / 256)   // 196 blocks for the sort kernels
#define SMAX 232                  // nodes cached in LDS (max graph ~195 expected)

__device__ __forceinline__ float lane_bcast(float v, int l) {
  return __int_as_float(__builtin_amdgcn_readlane(__float_as_int(v), l));
}

__device__ __forceinline__ float sigm(float x) {
  return 1.0f / (1.0f + expf(-x));
}

// --- 5 edge-type weight matrices: Wty[t][k*64+o] = relu(W_e1[t]+b_e1) @ W_e2 + b_e2
__global__ void k_edgemats(const float* __restrict__ W_e1, const float* __restrict__ b_e1,
                           const float* __restrict__ W_e2, const float* __restrict__ b_e2,
                           float* __restrict__ Wty) {
  __shared__ float v[HD];
  int t = blockIdx.x >> 2;       // 5 types
  int chunk = blockIdx.x & 3;    // 4 chunks of 1024
  int tid = threadIdx.x;
  if (tid < HD) {
    float x = W_e1[t * HD + tid] + b_e1[tid];
    v[tid] = x > 0.f ? x : 0.f;
  }
  __syncthreads();
  #pragma unroll
  for (int i = 0; i < 4; ++i) {
    int m = chunk * 1024 + i * 256 + tid;
    float acc = b_e2[m];
    #pragma unroll
    for (int j = 0; j < HD; ++j)
      acc = fmaf(v[j], W_e2[j * 4096 + m], acc);
    Wty[t * 4096 + m] = acc;
  }
}

// --- node embedding
__global__ void k_embed(const float* __restrict__ feat, const int* __restrict__ ntype,
                        const float* __restrict__ W_emb, const float* __restrict__ b_emb,
                        float* __restrict__ h) {
  int lane = threadIdx.x & 63;
  int n = (blockIdx.x * blockDim.x + threadIdx.x) >> 6;  // wave-uniform
  if (n >= NN) return;
  int t = ntype[n];                                       // broadcast load
  float fv = (lane < NFEAT) ? feat[n * NFEAT + lane] : 0.f;
  float acc = b_emb[lane] + W_emb[t * HD + lane];
  #pragma unroll
  for (int f = 0; f < NFEAT; ++f)
    acc = fmaf(lane_bcast(fv, f), W_emb[(NTYPES + f) * HD + lane], acc);
  h[n * HD + lane] = acc;
}

// --- atomic-free counting sort of edges by type (3 phases) ---
__global__ void k_cnt(const int* __restrict__ etype, int* __restrict__ bc) {
  int tid = threadIdx.x, lane = tid & 63, wv = tid >> 6;
  int e = blockIdx.x * 256 + tid;
  int ty = (e < NE) ? etype[e] : -1;
  __shared__ int wc[4][EDIM];
  #pragma unroll
  for (int t = 0; t < EDIM; ++t) {
    unsigned long long m = __ballot(ty == t);
    if (lane == 0) wc[wv][t] = __popcll(m);
  }
  __syncthreads();
  if (tid < EDIM) {
    int s = 0;
    #pragma unroll
    for (int w = 0; w < 4; ++w) s += wc[w][tid];
    bc[blockIdx.x * EDIM + tid] = s;
  }
}

// phase 2: parallel scan over NBLK block counts (one block, 256 threads)
__global__ void k_scan(const int* __restrict__ bc, int* __restrict__ blockbase,
                       int* __restrict__ offs) {
  __shared__ int buf[256];
  int tid = threadIdx.x;
  int running = 0;
  for (int t = 0; t < EDIM; ++t) {
    int v = (tid < NBLK) ? bc[tid * EDIM + t] : 0;
    buf[tid] = v;
    __syncthreads();
    #pragma unroll
    for (int off = 1; off < 256; off <<= 1) {
      int x = (tid >= off) ? buf[tid - off] : 0;
      __syncthreads();
      buf[tid] += x;
      __syncthreads();
    }
    int incl = buf[tid];
    int total = buf[255];
    if (tid < NBLK) blockbase[tid * EDIM + t] = running + incl - v;
    if (tid == 0) offs[t] = running;
    running += total;
    __syncthreads();
  }
  if (tid == 0) offs[EDIM] = running;
}

// phase 3: placement via ballot ranks; writes src/dst in sorted order
__global__ void k_place(const int* __restrict__ etype, const int* __restrict__ ei,
                        const int* __restrict__ blockbase,
                        int* __restrict__ srcs, int* __restrict__ dsts) {
  int tid = threadIdx.x, lane = tid & 63, wv = tid >> 6;
  int e = blockIdx.x * 256 + tid;
  int ty = (e < NE) ? etype[e] : -1;
  __shared__ int wc[4][EDIM];
  int rank = 0;
  #pragma unroll
  for (int t = 0; t < EDIM; ++t) {
    unsigned long long m = __ballot(ty == t);
    if (lane == 0) wc[wv][t] = __popcll(m);
    if (ty == t) rank = __popcll(m & ((1ull << lane) - 1ull));
  }
  __syncthreads();
  if (ty >= 0) {
    int base = blockbase[blockIdx.x * EDIM + ty];
    for (int w = 0; w < wv; ++w) base += wc[w][ty];
    int pos = base + rank;
    srcs[pos] = ei[e];
    dsts[pos] = ei[NE + e];
  }
}

// --- CSR starts for sorted batch vector ---
__global__ void k_starts(const int* __restrict__ batch, int* __restrict__ start) {
  int n = blockIdx.x * blockDim.x + threadIdx.x;
  if (n >= NN) return;
  int b = batch[n];
  if (n == 0)
    for (int t = 0; t <= b; ++t) start[t] = 0;
  int bn = (n + 1 < NN) ? batch[n + 1] : NB;
  for (int t = b + 1; t <= bn; ++t) start[t] = n + 1;
}

// --- root: hnext[n][o] = bias[o] + sum_k h[n][k]*root[k][o]  (also inits hnext)
__global__ void k_root(const float* __restrict__ h, float* __restrict__ hnext,
                       const float* __restrict__ root, const float* __restrict__ bias) {
  int lane = threadIdx.x & 63;
  int wid = blockIdx.x * (blockDim.x >> 6) + (threadIdx.x >> 6);
  int nw = gridDim.x * (blockDim.x >> 6);
  float w[HD];
  #pragma unroll
  for (int k = 0; k < HD; ++k) w[k] = root[k * HD + lane];
  float bb = bias[lane];
  for (int n = wid; n < NN; n += nw) {
    float hval = h[n * HD + lane];
    float a0 = 0.f, a1 = 0.f, a2 = 0.f, a3 = 0.f;
    #pragma unroll
    for (int k = 0; k < HD; k += 4) {
      a0 = fmaf(lane_bcast(hval, k + 0), w[k + 0], a0);
      a1 = fmaf(lane_bcast(hval, k + 1), w[k + 1], a1);
      a2 = fmaf(lane_bcast(hval, k + 2), w[k + 2], a2);
      a3 = fmaf(lane_bcast(hval, k + 3), w[k + 3], a3);
    }
    hnext[n * HD + lane] = bb + ((a0 + a1) + (a2 + a3));
  }
}

// --- edge messages: hnext[dst] += h[src] @ W_{type}; one wave per edge,
//     2-edge pipeline: both gathers in flight before either matvec.
__global__ __launch_bounds__(256) void k_msg(
    const int* __restrict__ srcs, const int* __restrict__ dsts,
    const int* __restrict__ offs, const float* __restrict__ Wty,
    const float* __restrict__ h, float* __restrict__ hnext) {
  int lane = threadIdx.x & 63;
  int wid = blockIdx.x * (blockDim.x >> 6) + (threadIdx.x >> 6);
  int nw = gridDim.x * (blockDim.x >> 6);
  int per = (NE + nw - 1) / nw;
  int beg = wid * per;
  int end = beg + per; if (end > NE) end = NE;
  if (beg >= end) return;
  for (int t = 0; t < EDIM; ++t) {
    int lo = offs[t];     if (lo < beg) lo = beg;
    int hi = offs[t + 1]; if (hi > end) hi = end;
    if (lo >= hi) continue;
    float w[HD];
    #pragma unroll
    for (int k = 0; k < HD; ++k) w[k] = Wty[t * 4096 + k * HD + lane];
    int p = lo;
    for (; p + 1 < hi; p += 2) {
      int s0 = srcs[p],     s1 = srcs[p + 1];
      int d0 = dsts[p],     d1 = dsts[p + 1];
      float h0 = h[s0 * HD + lane];
      float h1 = h[s1 * HD + lane];
      float a0 = 0.f, a1 = 0.f, a2 = 0.f, a3 = 0.f;
      float b0 = 0.f, b1 = 0.f, b2 = 0.f, b3 = 0.f;
      #pragma unroll
      for (int k = 0; k < HD; k += 4) {
        a0 = fmaf(lane_bcast(h0, k + 0), w[k + 0], a0);
        a1 = fmaf(lane_bcast(h0, k + 1), w[k + 1], a1);
        a2 = fmaf(lane_bcast(h0, k + 2), w[k + 2], a2);
        a3 = fmaf(lane_bcast(h0, k + 3), w[k + 3], a3);
        b0 = fmaf(lane_bcast(h1, k + 0), w[k + 0], b0);
        b1 = fmaf(lane_bcast(h1, k + 1), w[k + 1], b1);
        b2 = fmaf(lane_bcast(h1, k + 2), w[k + 2], b2);
        b3 = fmaf(lane_bcast(h1, k + 3), w[k + 3], b3);
      }
      atomicAdd(&hnext[d0 * HD + lane], (a0 + a1) + (a2 + a3));
      atomicAdd(&hnext[d1 * HD + lane], (b0 + b1) + (b2 + b3));
    }
    if (p < hi) {
      int s0 = srcs[p];
      int d0 = dsts[p];
      float h0 = h[s0 * HD + lane];
      float a0 = 0.f, a1 = 0.f, a2 = 0.f, a3 = 0.f;
      #pragma unroll
      for (int k = 0; k < HD; k += 4) {
        a0 = fmaf(lane_bcast(h0, k + 0), w[k + 0], a0);
        a1 = fmaf(lane_bcast(h0, k + 1), w[k + 1], a1);
        a2 = fmaf(lane_bcast(h0, k + 2), w[k + 2], a2);
        a3 = fmaf(lane_bcast(h0, k + 3), w[k + 3], a3);
      }
      atomicAdd(&hnext[d0 * HD + lane], (a0 + a1) + (a2 + a3));
    }
  }
}

// --- Set2Set + output MLP, one block per graph; graph nodes LDS-resident,
//     two-pass softmax (no serial online chain).
__global__ __launch_bounds__(256) void k_s2s(
    const float* __restrict__ h, const int* __restrict__ gstart,
    const float* __restrict__ W_ih, const float* __restrict__ W_hh,
    const float* __restrict__ b_ih, const float* __restrict__ b_hh,
    const float* __restrict__ W_o1, const float* __restrict__ b_o1,
    const float* __restrict__ W_o2, const float* __restrict__ b_o2,
    float* __restrict__ out) {
  __shared__ float hs[SMAX * HD];     // 58 KB
  __shared__ float ebuf[SMAX];
  __shared__ float qstar[2 * HD];
  __shared__ float hxs[HD], cxs[HD], gates[4 * HD];
  __shared__ float redM[4], redS[4], redR[4][HD];
  __shared__ float hid[HD];
  int b = blockIdx.x;
  int tid = threadIdx.x;
  int lane = tid & 63, wv = tid >> 6;
  int st = gstart[b], en = gstart[b + 1];
  int cnt = en - st;
  int cached = cnt < SMAX ? cnt : SMAX;

  // stage node block into LDS (coalesced float4)
  const float4* src4 = reinterpret_cast<const float4*>(h + st * HD);
  float4* dst4 = reinterpret_cast<float4*>(hs);
  int n4 = cached * (HD / 4);
  for (int i = tid; i < n4; i += 256) dst4[i] = src4[i];
  if (tid < 2 * HD) qstar[tid] = 0.f;
  if (tid < HD) { hxs[tid] = 0.f; cxs[tid] = 0.f; }
  __syncthreads();

  for (int it = 0; it < S2SIT; ++it) {
    // LSTM gates: tid = gate index in [0,256)
    float acc = b_ih[tid] + b_hh[tid];
    const float4* wi4 = reinterpret_cast<const float4*>(W_ih + tid * 2 * HD);
    #pragma unroll 8
    for (int j = 0; j < 32; ++j) {
      float4 wvv = wi4[j];
      acc = fmaf(qstar[4 * j + 0], wvv.x, acc);
      acc = fmaf(qstar[4 * j + 1], wvv.y, acc);
      acc = fmaf(qstar[4 * j + 2], wvv.z, acc);
      acc = fmaf(qstar[4 * j + 3], wvv.w, acc);
    }
    const float4* wh4 = reinterpret_cast<const float4*>(W_hh + tid * HD);
    #pragma unroll 8
    for (int j = 0; j < 16; ++j) {
      float4 wvv = wh4[j];
      acc = fmaf(hxs[4 * j + 0], wvv.x, acc);
      acc = fmaf(hxs[4 * j + 1], wvv.y, acc);
      acc = fmaf(hxs[4 * j + 2], wvv.z, acc);
      acc = fmaf(hxs[4 * j + 3], wvv.w, acc);
    }
    gates[tid] = acc;
    __syncthreads();
    if (tid < HD) {
      float ig = sigm(gates[tid]);
      float fg = sigm(gates[HD + tid]);
      float gg = tanhf(gates[2 * HD + tid]);
      float og = sigm(gates[3 * HD + tid]);
      float c = fmaf(fg, cxs[tid], ig * gg);
      cxs[tid] = c;
      hxs[tid] = og * tanhf(c);
    }
    __syncthreads();

    float q = hxs[lane];
    // pass 1: e[n] = <h_n, q> (independent dots, pipelineable) + running max
    float m = -1e30f;
    for (int n = wv; n < cached; n += 4) {
      float e = hs[n * HD + lane] * q;
      #pragma unroll
      for (int off = 32; off; off >>= 1) e += __shfl_xor(e, off, 64);
      if (lane == 0) ebuf[n] = e;
      m = fmaxf(m, e);
    }
    for (int n = SMAX + wv; n < cnt; n += 4) {  // overflow tail (normally empty)
      float e = h[(st + n) * HD + lane] * q;
      #pragma unroll
      for (int off = 32; off; off >>= 1) e += __shfl_xor(e, off, 64);
      m = fmaxf(m, e);
    }
    if (lane == 0) redM[wv] = m;
    __syncthreads();
    float M = fmaxf(fmaxf(redM[0], redM[1]), fmaxf(redM[2], redM[3]));

    // pass 2a: a[n] = exp(e[n]-M) into ebuf; partial sums
    float sp = 0.f;
    if (tid < cached) {
      float a = expf(ebuf[tid] - M);
      ebuf[tid] = a;
      sp = a;
    }
    #pragma unroll
    for (int off = 32; off; off >>= 1) sp += __shfl_xor(sp, off, 64);
    __syncthreads();  // ebuf(a) visible to all waves

    // pass 2b: r = sum_n a[n] * h_n  (LDS-broadcast FMA loop)
    float r = 0.f;
    for (int n = wv; n < cached; n += 4)
      r = fmaf(ebuf[n], hs[n * HD + lane], r);
    float s_tail = 0.f;
    for (int n = SMAX + wv; n < cnt; n += 4) {  // overflow tail
      float v = h[(st + n) * HD + lane];
      float e = v * q;
      #pragma unroll
      for (int off = 32; off; off >>= 1) e += __shfl_xor(e, off, 64);
      float a = expf(e - M);
      s_tail += a;
      r = fmaf(a, v, r);
    }
    if (lane == 0) redS[wv] = sp + s_tail;
    redR[wv][lane] = r;
    __syncthreads();
    if (tid < HD) {
      float S = redS[0] + redS[1] + redS[2] + redS[3];
      float R = redR[0][tid] + redR[1][tid] + redR[2][tid] + redR[3][tid];
      if (S == 0.f) S = 1.f;            // empty-graph guard (matches ref)
      qstar[tid] = hxs[tid];
      qstar[HD + tid] = R / S;
    }
    __syncthreads();
  }

  // output MLP: relu(qstar @ W_o1 + b_o1) @ W_o2 + b_o2
  if (tid < HD) {
    float acc = b_o1[tid];
    #pragma unroll 8
    for (int i = 0; i < 2 * HD; ++i)
      acc = fmaf(qstar[i], W_o1[i * HD + tid], acc);
    hid[tid] = acc > 0.f ? acc : 0.f;
  }
  __syncthreads();
  if (tid < HD) {
    float p = hid[tid] * W_o2[tid];
    #pragma unroll
    for (int off = 32; off; off >>= 1) p += __shfl_xor(p, off, 64);
    if (tid == 0) out[b] = p + b_o2[0];
  }
}

extern "C" void kernel_launch(void* const* d_in, const int* in_sizes, int n_in,
                              void* d_out, int out_size, void* d_ws, size_t ws_size,
                              hipStream_t stream) {
  const float* node_feat = (const float*)d_in[0];
  const int*   node_type = (const int*)d_in[1];
  const int*   edge_index= (const int*)d_in[2];
  const int*   edge_type = (const int*)d_in[3];
  const int*   batch     = (const int*)d_in[4];
  const float* W_emb     = (const float*)d_in[5];
  const float* b_emb     = (const float*)d_in[6];
  const float* W_e1      = (const float*)d_in[7];
  const float* b_e1      = (const float*)d_in[8];
  const float* W_e2      = (const float*)d_in[9];
  const float* b_e2      = (const float*)d_in[10];
  const float* roots     = (const float*)d_in[11];
  const float* conv_bias = (const float*)d_in[12];
  const float* W_ih      = (const float*)d_in[13];
  const float* W_hh      = (const float*)d_in[14];
  const float* b_ih      = (const float*)d_in[15];
  const float* b_hh      = (const float*)d_in[16];
  const float* W_o1      = (const float*)d_in[17];
  const float* b_o1      = (const float*)d_in[18];
  const float* W_o2      = (const float*)d_in[19];
  const float* b_o2      = (const float*)d_in[20];
  float* out = (float*)d_out;

  // workspace layout (floats/ints), base assumed 256B-aligned
  float* Wty    = (float*)d_ws;             // 5*4096
  float* hA     = Wty + EDIM * 4096;        // NN*64
  float* hB     = hA + NN * HD;             // NN*64
  int*   srcs   = (int*)(hB + NN * HD);     // NE
  int*   dsts   = srcs + NE;                // NE
  int*   bc     = dsts + NE;                // NBLK*EDIM
  int*   bbase  = bc + NBLK * EDIM;         // NBLK*EDIM
  int*   offs   = bbase + NBLK * EDIM;      // EDIM+1 (pad 8)
  int*   gstart = offs + 8;                 // NB+1

  k_edgemats<<<EDIM * 4, 256, 0, stream>>>(W_e1, b_e1, W_e2, b_e2, Wty);
  k_embed<<<(NN * HD) / 256, 256, 0, stream>>>(node_feat, node_type, W_emb, b_emb, hA);
  k_cnt<<<NBLK, 256, 0, stream>>>(edge_type, bc);
  k_scan<<<1, 256, 0, stream>>>(bc, bbase, offs);
  k_place<<<NBLK, 256, 0, stream>>>(edge_type, edge_index, bbase, srcs, dsts);
  k_starts<<<(NN + 255) / 256, 256, 0, stream>>>(batch, gstart);

  const float* hcur = hA;
  float* hnxt = hB;
  for (int i = 0; i < MPIT; ++i) {
    k_root<<<512, 256, 0, stream>>>(hcur, hnxt, roots + i * HD * HD, conv_bias + i * HD);
    k_msg<<<1024, 256, 0, stream>>>(srcs, dsts, offs, Wty, hcur, hnxt);
    const float* tmp = hnxt; hnxt = (float*)hcur; hcur = tmp;
  }

  k_s2s<<<NB, 256, 0, stream>>>(hcur, gstart, W_ih, W_hh, b_ih, b_hh,
                                W_o1, b_o1, W_o2, b_o2, out);
}

// Round 4
// 256.994 us; speedup vs baseline: 3.1507x; 1.2176x over previous
//
#include <hip/hip_runtime.h>
#include <math.h>

// ---------------------------------------------------------------------------
// MPNNPropPred: N=20000 nodes, E=50000 edges, B=128 graphs, H=64,
// FEAT=28, N_TYPES=100, EDGE_DIM=5, MP_ITER=3, S2S_IT=4, OUT=1. All f32.
// R4: k_s2s transposed attention (thread=node, padded LDS, no per-node shfl)
//     + pre-transposed LSTM weights (coalesced gate GEMV);
//     k_msg/k_root/k_embed use wave-uniform s_load rows (no readlanes).
// ---------------------------------------------------------------------------

#define NN 20000
#define NE 50000
#define NB 128
#define HD 64
#define NFEAT 28
#define NTYPES 100
#define EDIM 5
#define MPIT 3
#define S2SIT 4
#define NBLK ((NE + 255) / 256)   // 196 blocks for the sort kernels
#define SMAX 224                  // nodes cached in LDS (max graph ~195 expected)
#define HP (HD + 1)               // padded LDS row stride

__device__ __forceinline__ float sigm(float x) {
  return 1.0f / (1.0f + expf(-x));
}

// --- 5 edge-type weight matrices: Wty[t][k*64+o] = relu(W_e1[t]+b_e1) @ W_e2 + b_e2
__global__ void k_edgemats(const float* __restrict__ W_e1, const float* __restrict__ b_e1,
                           const float* __restrict__ W_e2, const float* __restrict__ b_e2,
                           float* __restrict__ Wty) {
  __shared__ float v[HD];
  int t = blockIdx.x >> 2;       // 5 types
  int chunk = blockIdx.x & 3;    // 4 chunks of 1024
  int tid = threadIdx.x;
  if (tid < HD) {
    float x = W_e1[t * HD + tid] + b_e1[tid];
    v[tid] = x > 0.f ? x : 0.f;
  }
  __syncthreads();
  #pragma unroll
  for (int i = 0; i < 4; ++i) {
    int m = chunk * 1024 + i * 256 + tid;
    float acc = b_e2[m];
    #pragma unroll
    for (int j = 0; j < HD; ++j)
      acc = fmaf(v[j], W_e2[j * 4096 + m], acc);
    Wty[t * 4096 + m] = acc;
  }
}

// --- transpose LSTM weights: W_ihT[j][g]=W_ih[g][j] (128x256), W_hhT (64x256)
__global__ void k_wT(const float* __restrict__ W_ih, const float* __restrict__ W_hh,
                     float* __restrict__ W_ihT, float* __restrict__ W_hhT) {
  int idx = blockIdx.x * 256 + threadIdx.x;   // 0..32767
  {
    int g = idx >> 7, j = idx & 127;          // W_ih [256][128]
    W_ihT[j * 256 + g] = W_ih[idx];
  }
  if (idx < 4 * HD * HD) {
    int g = idx >> 6, j = idx & 63;           // W_hh [256][64]
    W_hhT[j * 256 + g] = W_hh[idx];
  }
}

// --- node embedding (uniform feat row via scalar loads)
__global__ void k_embed(const float* __restrict__ feat, const int* __restrict__ ntype,
                        const float* __restrict__ W_emb, const float* __restrict__ b_emb,
                        float* __restrict__ h) {
  int lane = threadIdx.x & 63;
  int n = (blockIdx.x * blockDim.x + threadIdx.x) >> 6;
  if (n >= NN) return;
  int nu = __builtin_amdgcn_readfirstlane(n);
  int t = __builtin_amdgcn_readfirstlane(ntype[nu]);
  const float* row = feat + nu * NFEAT;       // wave-uniform -> s_load
  float acc = b_emb[lane] + W_emb[t * HD + lane];
  #pragma unroll
  for (int f = 0; f < NFEAT; ++f)
    acc = fmaf(row[f], W_emb[(NTYPES + f) * HD + lane], acc);
  h[nu * HD + lane] = acc;
}

// --- atomic-free counting sort of edges by type (3 phases) ---
__global__ void k_cnt(const int* __restrict__ etype, int* __restrict__ bc) {
  int tid = threadIdx.x, lane = tid & 63, wv = tid >> 6;
  int e = blockIdx.x * 256 + tid;
  int ty = (e < NE) ? etype[e] : -1;
  __shared__ int wc[4][EDIM];
  #pragma unroll
  for (int t = 0; t < EDIM; ++t) {
    unsigned long long m = __ballot(ty == t);
    if (lane == 0) wc[wv][t] = __popcll(m);
  }
  __syncthreads();
  if (tid < EDIM) {
    int s = 0;
    #pragma unroll
    for (int w = 0; w < 4; ++w) s += wc[w][tid];
    bc[blockIdx.x * EDIM + tid] = s;
  }
}

__global__ void k_scan(const int* __restrict__ bc, int* __restrict__ blockbase,
                       int* __restrict__ offs) {
  __shared__ int buf[256];
  int tid = threadIdx.x;
  int running = 0;
  for (int t = 0; t < EDIM; ++t) {
    int v = (tid < NBLK) ? bc[tid * EDIM + t] : 0;
    buf[tid] = v;
    __syncthreads();
    #pragma unroll
    for (int off = 1; off < 256; off <<= 1) {
      int x = (tid >= off) ? buf[tid - off] : 0;
      __syncthreads();
      buf[tid] += x;
      __syncthreads();
    }
    int incl = buf[tid];
    int total = buf[255];
    if (tid < NBLK) blockbase[tid * EDIM + t] = running + incl - v;
    if (tid == 0) offs[t] = running;
    running += total;
    __syncthreads();
  }
  if (tid == 0) offs[EDIM] = running;
}

__global__ void k_place(const int* __restrict__ etype, const int* __restrict__ ei,
                        const int* __restrict__ blockbase,
                        int* __restrict__ srcs, int* __restrict__ dsts) {
  int tid = threadIdx.x, lane = tid & 63, wv = tid >> 6;
  int e = blockIdx.x * 256 + tid;
  int ty = (e < NE) ? etype[e] : -1;
  __shared__ int wc[4][EDIM];
  int rank = 0;
  #pragma unroll
  for (int t = 0; t < EDIM; ++t) {
    unsigned long long m = __ballot(ty == t);
    if (lane == 0) wc[wv][t] = __popcll(m);
    if (ty == t) rank = __popcll(m & ((1ull << lane) - 1ull));
  }
  __syncthreads();
  if (ty >= 0) {
    int base = blockbase[blockIdx.x * EDIM + ty];
    for (int w = 0; w < wv; ++w) base += wc[w][ty];
    int pos = base + rank;
    srcs[pos] = ei[e];
    dsts[pos] = ei[NE + e];
  }
}

// --- CSR starts for sorted batch vector ---
__global__ void k_starts(const int* __restrict__ batch, int* __restrict__ start) {
  int n = blockIdx.x * blockDim.x + threadIdx.x;
  if (n >= NN) return;
  int b = batch[n];
  if (n == 0)
    for (int t = 0; t <= b; ++t) start[t] = 0;
  int bn = (n + 1 < NN) ? batch[n + 1] : NB;
  for (int t = b + 1; t <= bn; ++t) start[t] = n + 1;
}

// --- root: hnext[n][o] = bias[o] + sum_k h[n][k]*root[k][o]  (also inits hnext)
__global__ __launch_bounds__(256) void k_root(
    const float* __restrict__ h, float* __restrict__ hnext,
    const float* __restrict__ root, const float* __restrict__ bias) {
  int lane = threadIdx.x & 63;
  int wid = __builtin_amdgcn_readfirstlane(blockIdx.x * 4 + (threadIdx.x >> 6));
  int nw = gridDim.x * 4;
  float w[HD];
  #pragma unroll
  for (int k = 0; k < HD; ++k) w[k] = root[k * HD + lane];
  float bb = bias[lane];
  for (int n = wid; n < NN; n += nw) {
    const float* row = h + n * HD;            // wave-uniform -> s_load
    float a0 = 0.f, a1 = 0.f, a2 = 0.f, a3 = 0.f;
    #pragma unroll
    for (int k = 0; k < HD; k += 4) {
      a0 = fmaf(row[k + 0], w[k + 0], a0);
      a1 = fmaf(row[k + 1], w[k + 1], a1);
      a2 = fmaf(row[k + 2], w[k + 2], a2);
      a3 = fmaf(row[k + 3], w[k + 3], a3);
    }
    hnext[n * HD + lane] = bb + ((a0 + a1) + (a2 + a3));
  }
}

// --- edge messages: hnext[dst] += h[src] @ W_{type}; one wave per edge,
//     h row via wave-uniform scalar loads (no readlane), W column in VGPRs.
__global__ __launch_bounds__(256) void k_msg(
    const int* __restrict__ srcs, const int* __restrict__ dsts,
    const int* __restrict__ offs, const float* __restrict__ Wty,
    const float* __restrict__ h, float* __restrict__ hnext) {
  int lane = threadIdx.x & 63;
  int wid = __builtin_amdgcn_readfirstlane(blockIdx.x * 4 + (threadIdx.x >> 6));
  int nw = gridDim.x * 4;
  int per = (NE + nw - 1) / nw;
  int beg = wid * per;
  int end = beg + per; if (end > NE) end = NE;
  if (beg >= end) return;
  for (int t = 0; t < EDIM; ++t) {
    int lo = offs[t];     if (lo < beg) lo = beg;
    int hi = offs[t + 1]; if (hi > end) hi = end;
    if (lo >= hi) continue;
    float w[HD];
    #pragma unroll
    for (int k = 0; k < HD; ++k) w[k] = Wty[t * 4096 + k * HD + lane];
    for (int p = lo; p < hi; ++p) {
      int s = __builtin_amdgcn_readfirstlane(srcs[p]);
      int d = __builtin_amdgcn_readfirstlane(dsts[p]);
      const float* row = h + s * HD;          // wave-uniform -> s_load
      float a0 = 0.f, a1 = 0.f, a2 = 0.f, a3 = 0.f;
      #pragma unroll
      for (int k = 0; k < HD; k += 4) {
        a0 = fmaf(row[k + 0], w[k + 0], a0);
        a1 = fmaf(row[k + 1], w[k + 1], a1);
        a2 = fmaf(row[k + 2], w[k + 2], a2);
        a3 = fmaf(row[k + 3], w[k + 3], a3);
      }
      atomicAdd(&hnext[d * HD + lane], (a0 + a1) + (a2 + a3));
    }
  }
}

// --- Set2Set + output MLP, one block per graph; padded LDS node cache,
//     transposed attention (thread = node, no per-node shuffles).
__global__ __launch_bounds__(256) void k_s2s(
    const float* __restrict__ h, const int* __restrict__ gstart,
    const float* __restrict__ W_ihT, const float* __restrict__ W_hhT,
    const float* __restrict__ b_ih, const float* __restrict__ b_hh,
    const float* __restrict__ W_o1, const float* __restrict__ b_o1,
    const float* __restrict__ W_o2, const float* __restrict__ b_o2,
    float* __restrict__ out) {
  __shared__ float hs[SMAX * HP];     // 58240 B, padded rows
  __shared__ float ebuf[SMAX];
  __shared__ float qstar[2 * HD];
  __shared__ float hxs[HD], cxs[HD], gates[4 * HD];
  __shared__ float redM[4], redS[4], redR[4][HD];
  __shared__ float hid[HD];
  int b = blockIdx.x;
  int tid = threadIdx.x;
  int lane = tid & 63, wv = tid >> 6;
  int st = gstart[b], en = gstart[b + 1];
  int cnt = en - st;
  int cached = cnt < SMAX ? cnt : SMAX;

  // stage node block into padded LDS (coalesced float4 global reads)
  int total = cached * HD;
  for (int base = tid * 4; base < total; base += 1024) {
    float4 v = *reinterpret_cast<const float4*>(h + st * HD + base);
    int n = base >> 6, k = base & 63;
    float* row = hs + n * HP + k;
    row[0] = v.x; row[1] = v.y; row[2] = v.z; row[3] = v.w;
  }
  if (tid < 2 * HD) qstar[tid] = 0.f;
  if (tid < HD) { hxs[tid] = 0.f; cxs[tid] = 0.f; }
  __syncthreads();

  for (int it = 0; it < S2SIT; ++it) {
    // LSTM gates via transposed weights (coalesced): tid = gate index
    float acc0 = b_ih[tid] + b_hh[tid], acc1 = 0.f;
    #pragma unroll 8
    for (int j = 0; j < 2 * HD; j += 2) {
      acc0 = fmaf(qstar[j],     W_ihT[j * 256 + tid],       acc0);
      acc1 = fmaf(qstar[j + 1], W_ihT[(j + 1) * 256 + tid], acc1);
    }
    #pragma unroll 8
    for (int j = 0; j < HD; j += 2) {
      acc0 = fmaf(hxs[j],     W_hhT[j * 256 + tid],       acc0);
      acc1 = fmaf(hxs[j + 1], W_hhT[(j + 1) * 256 + tid], acc1);
    }
    gates[tid] = acc0 + acc1;
    __syncthreads();
    if (tid < HD) {
      float ig = sigm(gates[tid]);
      float fg = sigm(gates[HD + tid]);
      float gg = tanhf(gates[2 * HD + tid]);
      float og = sigm(gates[3 * HD + tid]);
      float c = fmaf(fg, cxs[tid], ig * gg);
      cxs[tid] = c;
      hxs[tid] = og * tanhf(c);
    }
    __syncthreads();

    // pass 1: per-thread dot (thread = node), padded LDS rows (conflict-free)
    float e = -1e30f;
    if (tid < cached) {
      const float* row = hs + tid * HP;
      float d0 = 0.f, d1 = 0.f;
      #pragma unroll 8
      for (int k = 0; k < HD; k += 2) {
        d0 = fmaf(row[k],     hxs[k],     d0);
        d1 = fmaf(row[k + 1], hxs[k + 1], d1);
      }
      e = d0 + d1;
      ebuf[tid] = e;
    }
    float m = e;
    #pragma unroll
    for (int off = 32; off; off >>= 1) m = fmaxf(m, __shfl_xor(m, off, 64));
    float qreg = hxs[lane];
    for (int n = cached + wv; n < cnt; n += 4) {   // overflow tail (normally empty)
      float ev = h[(st + n) * HD + lane] * qreg;
      #pragma unroll
      for (int off = 32; off; off >>= 1) ev += __shfl_xor(ev, off, 64);
      m = fmaxf(m, ev);
    }
    if (lane == 0) redM[wv] = m;
    __syncthreads();
    float M = fmaxf(fmaxf(redM[0], redM[1]), fmaxf(redM[2], redM[3]));

    // pass 2a: a = exp(e-M), per-wave partial sum
    float sp = 0.f;
    if (tid < cached) {
      float a = expf(ebuf[tid] - M);
      ebuf[tid] = a;
      sp = a;
    }
    #pragma unroll
    for (int off = 32; off; off >>= 1) sp += __shfl_xor(sp, off, 64);
    __syncthreads();   // ebuf(a) visible to all waves

    // pass 2b: r = sum_n a[n] * h_n  (lane = feature)
    float r = 0.f;
    for (int n = wv; n < cached; n += 4)
      r = fmaf(ebuf[n], hs[n * HP + lane], r);
    float s_tail = 0.f;
    for (int n = cached + wv; n < cnt; n += 4) {   // overflow tail
      float v = h[(st + n) * HD + lane];
      float ev = v * qreg;
      #pragma unroll
      for (int off = 32; off; off >>= 1) ev += __shfl_xor(ev, off, 64);
      float a = expf(ev - M);
      s_tail += a;
      r = fmaf(a, v, r);
    }
    if (lane == 0) redS[wv] = sp + s_tail;
    redR[wv][lane] = r;
    __syncthreads();
    if (tid < HD) {
      float S = redS[0] + redS[1] + redS[2] + redS[3];
      float R = redR[0][tid] + redR[1][tid] + redR[2][tid] + redR[3][tid];
      if (S == 0.f) S = 1.f;            // empty-graph guard (matches ref)
      qstar[tid] = hxs[tid];
      qstar[HD + tid] = R / S;
    }
    __syncthreads();
  }

  // output MLP: relu(qstar @ W_o1 + b_o1) @ W_o2 + b_o2
  if (tid < HD) {
    float acc = b_o1[tid];
    #pragma unroll 8
    for (int i = 0; i < 2 * HD; ++i)
      acc = fmaf(qstar[i], W_o1[i * HD + tid], acc);
    hid[tid] = acc > 0.f ? acc : 0.f;
  }
  __syncthreads();
  if (tid < HD) {
    float p = hid[tid] * W_o2[tid];
    #pragma unroll
    for (int off = 32; off; off >>= 1) p += __shfl_xor(p, off, 64);
    if (tid == 0) out[b] = p + b_o2[0];
  }
}

extern "C" void kernel_launch(void* const* d_in, const int* in_sizes, int n_in,
                              void* d_out, int out_size, void* d_ws, size_t ws_size,
                              hipStream_t stream) {
  const float* node_feat = (const float*)d_in[0];
  const int*   node_type = (const int*)d_in[1];
  const int*   edge_index= (const int*)d_in[2];
  const int*   edge_type = (const int*)d_in[3];
  const int*   batch     = (const int*)d_in[4];
  const float* W_emb     = (const float*)d_in[5];
  const float* b_emb     = (const float*)d_in[6];
  const float* W_e1      = (const float*)d_in[7];
  const float* b_e1      = (const float*)d_in[8];
  const float* W_e2      = (const float*)d_in[9];
  const float* b_e2      = (const float*)d_in[10];
  const float* roots     = (const float*)d_in[11];
  const float* conv_bias = (const float*)d_in[12];
  const float* W_ih      = (const float*)d_in[13];
  const float* W_hh      = (const float*)d_in[14];
  const float* b_ih      = (const float*)d_in[15];
  const float* b_hh      = (const float*)d_in[16];
  const float* W_o1      = (const float*)d_in[17];
  const float* b_o1      = (const float*)d_in[18];
  const float* W_o2      = (const float*)d_in[19];
  const float* b_o2      = (const float*)d_in[20];
  float* out = (float*)d_out;

  // workspace layout (floats/ints), base assumed 256B-aligned
  float* Wty    = (float*)d_ws;             // 5*4096
  float* hA     = Wty + EDIM * 4096;        // NN*64
  float* hB     = hA + NN * HD;             // NN*64
  float* W_ihT  = hB + NN * HD;             // 128*256
  float* W_hhT  = W_ihT + 2 * HD * 4 * HD;  // 64*256
  int*   srcs   = (int*)(W_hhT + HD * 4 * HD); // NE
  int*   dsts   = srcs + NE;                // NE
  int*   bc     = dsts + NE;                // NBLK*EDIM
  int*   bbase  = bc + NBLK * EDIM;         // NBLK*EDIM
  int*   offs   = bbase + NBLK * EDIM;      // EDIM+1 (pad 8)
  int*   gstart = offs + 8;                 // NB+1

  k_edgemats<<<EDIM * 4, 256, 0, stream>>>(W_e1, b_e1, W_e2, b_e2, Wty);
  k_wT<<<128, 256, 0, stream>>>(W_ih, W_hh, W_ihT, W_hhT);
  k_embed<<<(NN * HD) / 256, 256, 0, stream>>>(node_feat, node_type, W_emb, b_emb, hA);
  k_cnt<<<NBLK, 256, 0, stream>>>(edge_type, bc);
  k_scan<<<1, 256, 0, stream>>>(bc, bbase, offs);
  k_place<<<NBLK, 256, 0, stream>>>(edge_type, edge_index, bbase, srcs, dsts);
  k_starts<<<(NN + 255) / 256, 256, 0, stream>>>(batch, gstart);

  const float* hcur = hA;
  float* hnxt = hB;
  for (int i = 0; i < MPIT; ++i) {
    k_root<<<512, 256, 0, stream>>>(hcur, hnxt, roots + i * HD * HD, conv_bias + i * HD);
    k_msg<<<2048, 256, 0, stream>>>(srcs, dsts, offs, Wty, hcur, hnxt);
    const float* tmp = hnxt; hnxt = (float*)hcur; hcur = tmp;
  }

  k_s2s<<<NB, 256, 0, stream>>>(hcur, gstart, W_ihT, W_hhT, b_ih, b_hh,
                                W_o1, b_o1, W_o2, b_o2, out);
}